// Round 1
// baseline (4194.444 us; speedup 1.0000x reference)
//
#include <hip/hip_runtime.h>

// ComplexAttention: B=16, S=1024, D=1024.
// d_in order: 0 q_real, 1 q_imag, 2 k_real, 3 k_imag, 4 v_real, 5 v_imag,
//             6 Wq_r, 7 bq_r, 8 Wq_i, 9 bq_i, 10 Wk_r, 11 bk_r, 12 Wk_i, 13 bk_i,
//             14 Wv_r, 15 bv_r, 16 Wv_i, 17 bv_i, 18 a_2, 19 b_2
// ws layout (floats): P[0..5] = qr,qi,kr,ki,vr,vi (each 16M), S = scores/attn (16M).
// All-f32 compute: the complex-LN divides by sqrt(var+eps) where var nearly cancels
// (|y|max ~ 454) -> relative error in z amplified ~400-13000x; fp16/bf16 GEMM inputs
// would fail the 3.64 threshold. f32 baseline first; split-fp16 MFMA later rounds.

#define TSIZE 16777216L   // 16*1024*1024
#define BSTRIDE 1048576L  // 1024*1024

__device__ __forceinline__ float wave_sum(float x) {
#pragma unroll
  for (int o = 32; o; o >>= 1) x += __shfl_xor(x, o);
  return x;
}
__device__ __forceinline__ float wave_max(float x) {
#pragma unroll
  for (int o = 32; o; o >>= 1) x = fmaxf(x, __shfl_xor(x, o));
  return x;
}

// C[m,n] (+)= scale * sum_k A[m,k] * B[.,.] (+ bias[n])
// B_NT: B is [N,K] row-major (y = x @ W^T style). else B is [K,N] row-major.
// Tile 128x128, BK=16, 256 threads, 8x8 per-thread micro-tile (4+4 split).
template <bool B_NT, bool ACCUM>
__launch_bounds__(256, 4)
__global__ void gemm128(const float* __restrict__ A, const float* __restrict__ B,
                        const float* __restrict__ bias, float* __restrict__ C,
                        float scale, long sA, long sB, long sC) {
  constexpr int BK = 16;
  const int bn0 = blockIdx.x * 128;
  const int bm0 = blockIdx.y * 128;
  A += (long)blockIdx.z * sA;
  B += (long)blockIdx.z * sB;
  C += (long)blockIdx.z * sC;

  __shared__ float As[BK][128];
  __shared__ float Bs[BK][128];

  const int tid = threadIdx.x;
  const int arow = tid >> 1;         // 0..127
  const int akc = (tid & 1) * 8;     // 0 or 8 (k chunk)
  const int bkr = tid >> 4;          // NN: k row 0..15
  const int bnc = (tid & 15) * 8;    // NN: col chunk
  const int tx = tid & 15;
  const int ty = tid >> 4;

  float acc[8][8];
#pragma unroll
  for (int i = 0; i < 8; ++i)
#pragma unroll
    for (int j = 0; j < 8; ++j) acc[i][j] = 0.f;

  const float* Ap = A + (long)(bm0 + arow) * 1024 + akc;
  const float* Bnt = B + (long)(bn0 + arow) * 1024 + akc;
  const float* Bnn = B + (long)bkr * 1024 + bn0 + bnc;

  for (int k0 = 0; k0 < 1024; k0 += BK) {
    __syncthreads();
    {
      float4 a0 = *(const float4*)(Ap + k0);
      float4 a1 = *(const float4*)(Ap + k0 + 4);
      As[akc + 0][arow] = a0.x; As[akc + 1][arow] = a0.y;
      As[akc + 2][arow] = a0.z; As[akc + 3][arow] = a0.w;
      As[akc + 4][arow] = a1.x; As[akc + 5][arow] = a1.y;
      As[akc + 6][arow] = a1.z; As[akc + 7][arow] = a1.w;
    }
    if (B_NT) {
      float4 b0 = *(const float4*)(Bnt + k0);
      float4 b1 = *(const float4*)(Bnt + k0 + 4);
      Bs[akc + 0][arow] = b0.x; Bs[akc + 1][arow] = b0.y;
      Bs[akc + 2][arow] = b0.z; Bs[akc + 3][arow] = b0.w;
      Bs[akc + 4][arow] = b1.x; Bs[akc + 5][arow] = b1.y;
      Bs[akc + 6][arow] = b1.z; Bs[akc + 7][arow] = b1.w;
    } else {
      float4 b0 = *(const float4*)(Bnn + (long)k0 * 1024);
      float4 b1 = *(const float4*)(Bnn + (long)k0 * 1024 + 4);
      *(float4*)&Bs[bkr][bnc] = b0;
      *(float4*)&Bs[bkr][bnc + 4] = b1;
    }
    __syncthreads();
#pragma unroll
    for (int kk = 0; kk < BK; ++kk) {
      float4 aL = *(const float4*)&As[kk][ty * 4];
      float4 aH = *(const float4*)&As[kk][64 + ty * 4];
      float4 bL = *(const float4*)&Bs[kk][tx * 4];
      float4 bH = *(const float4*)&Bs[kk][64 + tx * 4];
      float a[8] = {aL.x, aL.y, aL.z, aL.w, aH.x, aH.y, aH.z, aH.w};
      float b[8] = {bL.x, bL.y, bL.z, bL.w, bH.x, bH.y, bH.z, bH.w};
#pragma unroll
      for (int i = 0; i < 8; ++i)
#pragma unroll
        for (int j = 0; j < 8; ++j) acc[i][j] = fmaf(a[i], b[j], acc[i][j]);
    }
  }

  float bc0[4] = {0.f, 0.f, 0.f, 0.f}, bc1[4] = {0.f, 0.f, 0.f, 0.f};
  if (bias) {
    float4 t0 = *(const float4*)(bias + bn0 + tx * 4);
    float4 t1 = *(const float4*)(bias + bn0 + 64 + tx * 4);
    bc0[0] = t0.x; bc0[1] = t0.y; bc0[2] = t0.z; bc0[3] = t0.w;
    bc1[0] = t1.x; bc1[1] = t1.y; bc1[2] = t1.z; bc1[3] = t1.w;
  }
#pragma unroll
  for (int ih = 0; ih < 2; ++ih) {
#pragma unroll
    for (int i = 0; i < 4; ++i) {
      const long row = bm0 + ih * 64 + ty * 4 + i;
#pragma unroll
      for (int jh = 0; jh < 2; ++jh) {
        const int col = bn0 + jh * 64 + tx * 4;
        float* cp = C + row * 1024 + col;
        const float* bc = jh ? bc1 : bc0;
        float4 v;
        v.x = acc[ih * 4 + i][jh * 4 + 0] * scale + bc[0];
        v.y = acc[ih * 4 + i][jh * 4 + 1] * scale + bc[1];
        v.z = acc[ih * 4 + i][jh * 4 + 2] * scale + bc[2];
        v.w = acc[ih * 4 + i][jh * 4 + 3] * scale + bc[3];
        if (ACCUM) {
          float4 o = *(const float4*)cp;
          v.x += o.x; v.y += o.y; v.z += o.z; v.w += o.w;
        }
        *(float4*)cp = v;
      }
    }
  }
}

// Row softmax over 1024, in place. One block per row.
__launch_bounds__(256)
__global__ void softmax1024(float* __restrict__ S) {
  const long row = blockIdx.x;
  float* p = S + row * 1024;
  const int tid = threadIdx.x;
  float4 v = *(const float4*)(p + tid * 4);
  float m = fmaxf(fmaxf(v.x, v.y), fmaxf(v.z, v.w));
  m = wave_max(m);
  __shared__ float redm[4];
  __shared__ float reds[4];
  const int wave = tid >> 6, lane = tid & 63;
  if (lane == 0) redm[wave] = m;
  __syncthreads();
  m = fmaxf(fmaxf(redm[0], redm[1]), fmaxf(redm[2], redm[3]));
  v.x = __expf(v.x - m); v.y = __expf(v.y - m);
  v.z = __expf(v.z - m); v.w = __expf(v.w - m);
  float s = v.x + v.y + v.z + v.w;
  s = wave_sum(s);
  if (lane == 0) reds[wave] = s;
  __syncthreads();
  s = reds[0] + reds[1] + reds[2] + reds[3];
  const float inv = 1.0f / s;
  v.x *= inv; v.y *= inv; v.z *= inv; v.w *= inv;
  *(float4*)(p + tid * 4) = v;
}

// Complex layernorm over last dim (1024), in place on d_out:
// z = out[0] + i*out[1]; mean/var complex; std = csqrt(var+eps);
// y = a2*( (z-mean)/std ) + b2 (b2 adds to real part only).
__launch_bounds__(256)
__global__ void complex_ln(float* __restrict__ out, const float* __restrict__ a2,
                           const float* __restrict__ b2) {
  const long row = blockIdx.x;
  float* xr = out + row * 1024;
  float* xi = out + TSIZE + row * 1024;
  const int tid = threadIdx.x;
  float4 r4 = *(const float4*)(xr + tid * 4);
  float4 i4 = *(const float4*)(xi + tid * 4);
  float sx = r4.x + r4.y + r4.z + r4.w;
  float sy = i4.x + i4.y + i4.z + i4.w;
  float sxx = r4.x * r4.x + r4.y * r4.y + r4.z * r4.z + r4.w * r4.w;
  float syy = i4.x * i4.x + i4.y * i4.y + i4.z * i4.z + i4.w * i4.w;
  float sxy = r4.x * i4.x + r4.y * i4.y + r4.z * i4.z + r4.w * i4.w;
  sx = wave_sum(sx); sy = wave_sum(sy);
  sxx = wave_sum(sxx); syy = wave_sum(syy); sxy = wave_sum(sxy);
  __shared__ float red[4][5];
  const int wave = tid >> 6, lane = tid & 63;
  if (lane == 0) {
    red[wave][0] = sx; red[wave][1] = sy; red[wave][2] = sxx;
    red[wave][3] = syy; red[wave][4] = sxy;
  }
  __syncthreads();
  sx = red[0][0] + red[1][0] + red[2][0] + red[3][0];
  sy = red[0][1] + red[1][1] + red[2][1] + red[3][1];
  sxx = red[0][2] + red[1][2] + red[2][2] + red[3][2];
  syy = red[0][3] + red[1][3] + red[2][3] + red[3][3];
  sxy = red[0][4] + red[1][4] + red[2][4] + red[3][4];
  const float invN = 1.0f / 1024.0f;
  const float mx = sx * invN, my = sy * invN;
  const float vx = (sxx * invN - mx * mx) - (syy * invN - my * my);
  const float vy = 2.0f * (sxy * invN - mx * my);
  const float wx = vx + 1e-6f, wy = vy;
  const float rm = sqrtf(wx * wx + wy * wy);
  const float sre = sqrtf(fmaxf(rm + wx, 0.0f) * 0.5f);
  const float sim = copysignf(sqrtf(fmaxf(rm - wx, 0.0f) * 0.5f), wy);
  const float ir = 1.0f / fmaxf(rm, 1e-30f);  // |std|^2 = rm
  float4 a4 = *(const float4*)(a2 + tid * 4);
  float4 b4 = *(const float4*)(b2 + tid * 4);
  float4 orr, oii;
  {
    float zx = r4.x - mx, zy = i4.x - my;
    orr.x = a4.x * ((zx * sre + zy * sim) * ir) + b4.x;
    oii.x = a4.x * ((zy * sre - zx * sim) * ir);
  }
  {
    float zx = r4.y - mx, zy = i4.y - my;
    orr.y = a4.y * ((zx * sre + zy * sim) * ir) + b4.y;
    oii.y = a4.y * ((zy * sre - zx * sim) * ir);
  }
  {
    float zx = r4.z - mx, zy = i4.z - my;
    orr.z = a4.z * ((zx * sre + zy * sim) * ir) + b4.z;
    oii.z = a4.z * ((zy * sre - zx * sim) * ir);
  }
  {
    float zx = r4.w - mx, zy = i4.w - my;
    orr.w = a4.w * ((zx * sre + zy * sim) * ir) + b4.w;
    oii.w = a4.w * ((zy * sre - zx * sim) * ir);
  }
  *(float4*)(xr + tid * 4) = orr;
  *(float4*)(xi + tid * 4) = oii;
}

extern "C" void kernel_launch(void* const* d_in, const int* in_sizes, int n_in,
                              void* d_out, int out_size, void* d_ws, size_t ws_size,
                              hipStream_t stream) {
  const float* X[6];
  for (int i = 0; i < 6; ++i) X[i] = (const float*)d_in[i];
  const float* W[6];
  const float* bia[6];
  for (int i = 0; i < 6; ++i) {
    W[i] = (const float*)d_in[6 + 2 * i];
    bia[i] = (const float*)d_in[7 + 2 * i];
  }
  const float* a2 = (const float*)d_in[18];
  const float* b2 = (const float*)d_in[19];

  float* ws = (float*)d_ws;
  float* P[6];
  for (int i = 0; i < 6; ++i) P[i] = ws + (long)i * TSIZE;
  float* S = ws + 6L * TSIZE;
  float* out = (float*)d_out;

  dim3 blk(256);
  dim3 gproj(8, 128, 1);
  dim3 gbat(8, 8, 16);

  // 6 projections: P[i] = X[i] @ W[i]^T + b[i]
  for (int i = 0; i < 6; ++i)
    gemm128<true, false><<<gproj, blk, 0, stream>>>(X[i], W[i], bia[i], P[i], 1.0f, 0, 0, 0);

  // scores = 0.125*(qr @ kr  +  qi @ ki^T)   (batched over 16)
  gemm128<false, false><<<gbat, blk, 0, stream>>>(P[0], P[2], nullptr, S, 0.125f,
                                                  BSTRIDE, BSTRIDE, BSTRIDE);
  gemm128<true, true><<<gbat, blk, 0, stream>>>(P[1], P[3], nullptr, S, 0.125f,
                                                BSTRIDE, BSTRIDE, BSTRIDE);

  // softmax rows (in place -> attn)
  softmax1024<<<dim3(16384), blk, 0, stream>>>(S);

  // out_r = attn @ vr ; out_i = attn @ vi
  gemm128<false, false><<<gbat, blk, 0, stream>>>(S, P[4], nullptr, out, 1.0f,
                                                  BSTRIDE, BSTRIDE, BSTRIDE);
  gemm128<false, false><<<gbat, blk, 0, stream>>>(S, P[5], nullptr, out + TSIZE, 1.0f,
                                                  BSTRIDE, BSTRIDE, BSTRIDE);

  // complex layernorm in place on d_out
  complex_ln<<<dim3(16384), blk, 0, stream>>>(out, a2, b2);
}

// Round 2
// 1912.611 us; speedup vs baseline: 2.1930x; 2.1930x over previous
//
#include <hip/hip_runtime.h>

// ComplexAttention B=16, S=D=1024 — split-fp16 MFMA pipeline.
// Precision: operands split f32 -> (hi,lo) fp16; products Ahi*Bhi + Ahi*Blo + Alo*Bhi
// accumulate in f32 via v_mfma_f32_32x32x16_f16 (dropped Alo*Blo ~ 2^-22 rel).
// SP (split-pair) tensor layout: [row][kc=k/8] -> 16B hi-unit, 16B lo-unit
// (row stride 4096 B for K=1024). MFMA frag = 8 consecutive k of one component = 1 unit.
//
// ws (408 MB): qr_sp 64MB | qi_sp | ki_sp | krT_sp | vrT_sp | viT_sp | Wsp 6x4MB
// d_out used as scratch: [0:64MB) Xsp then S(f32); [64:128MB) F0(f32) then attn_sp.
// out_r/out_i f32 overwrite qr_sp/qi_sp (dead after scores). LN: ws -> d_out.

#define MB 1048576L

typedef _Float16 h8 __attribute__((ext_vector_type(8)));
typedef _Float16 h4 __attribute__((ext_vector_type(4)));
typedef float f32x16 __attribute__((ext_vector_type(16)));

__device__ __forceinline__ float wave_sum(float x) {
#pragma unroll
  for (int o = 32; o; o >>= 1) x += __shfl_xor(x, o);
  return x;
}
__device__ __forceinline__ float wave_max(float x) {
#pragma unroll
  for (int o = 32; o; o >>= 1) x = fmaxf(x, __shfl_xor(x, o));
  return x;
}

__device__ __forceinline__ void async16(const char* g, char* l) {
  __builtin_amdgcn_global_load_lds(
      (const __attribute__((address_space(1))) unsigned int*)g,
      (__attribute__((address_space(3))) unsigned int*)l, 16, 0, 0);
}

// f32 x8 -> hi8/lo8 fp16
__device__ __forceinline__ void split8(const float* v, h8& hi, h8& lo) {
#pragma unroll
  for (int j = 0; j < 8; ++j) {
    _Float16 h = (_Float16)v[j];
    hi[j] = h;
    lo[j] = (_Float16)(v[j] - (float)h);
  }
}

// straight split: in f32[n8*8] -> out SP units (32B per 8 elems)
__global__ void split_pass(const float* __restrict__ in, char* __restrict__ out, long n8) {
  long i = (long)blockIdx.x * blockDim.x + threadIdx.x;
  if (i >= n8) return;
  float v[8];
  const float4* p = (const float4*)(in + i * 8);
  float4 a = p[0], b = p[1];
  v[0] = a.x; v[1] = a.y; v[2] = a.z; v[3] = a.w;
  v[4] = b.x; v[5] = b.y; v[6] = b.z; v[7] = b.w;
  h8 hi, lo;
  split8(v, hi, lo);
  *(h8*)(out + i * 32) = hi;
  *(h8*)(out + i * 32 + 16) = lo;
}

// Split-fp16 MFMA GEMM: C[128x128 tile] = scale * sum_pairs A_sp @ B_sp^T (+bias)
// A_sp: [M][K] k-contig SP; B_sp: [N][K] k-contig SP; K=1024 per pair.
// EPI 0: f32 store (opt bias, scale). EPI 1: split-pair TRANSPOSED store (bias):
//   Ct[b][n][k=row%1024] for projections (rows = b*1024+s).
template <int EPI>
__launch_bounds__(256, 3)
__global__ void gemm_sp(const char* __restrict__ A1, const char* __restrict__ B1,
                        const char* __restrict__ A2, const char* __restrict__ B2,
                        int npair, const float* __restrict__ bias,
                        float* __restrict__ Cf, char* __restrict__ Ct,
                        float scale, long zA, long zB, long zC) {
  __shared__ __align__(16) char lds[32768];  // A [0,16K), B [16K,32K)
  const int tid = threadIdx.x;
  const int wid = tid >> 6, lane = tid & 63;
  const int ln31 = lane & 31, half = lane >> 5;
  const int bm0 = blockIdx.y * 128, bn0 = blockIdx.x * 128;
  const long z = blockIdx.z;

  const char* Ap[2] = {A1 + z * zA, A2 ? A2 + z * zA : nullptr};
  const char* Bp[2] = {B1 + z * zB, B2 ? B2 + z * zB : nullptr};

  // staging: wave stages A rows [wid*32, wid*32+32) and B rows likewise,
  // 4 instrs each of 8 rows x 8 units; lane -> (row=srow, unit=sunit XOR-swizzled)
  const int srow = lane >> 3;
  const int sunit = (lane & 7) ^ srow;
  char* ldsA = lds + wid * 4096;
  char* ldsB = lds + 16384 + wid * 4096;

  // frag read bases
  const int e = ln31 & 7;
  const int rowA0 = ((wid >> 1) * 64 + ln31) * 128;
  const int rowB0 = 16384 + ((wid & 1) * 64 + ln31) * 128;
  int uoff[2][2];
#pragma unroll
  for (int ks = 0; ks < 2; ++ks)
#pragma unroll
    for (int c = 0; c < 2; ++c) uoff[ks][c] = ((4 * ks + 2 * half + c) ^ e) * 16;

  f32x16 acc[2][2] = {};

  for (int p = 0; p < npair; ++p) {
    const char* a0 = Ap[p] + (long)(bm0 + wid * 32 + srow) * 4096 + sunit * 16;
    const char* b0 = Bp[p] + (long)(bn0 + wid * 32 + srow) * 4096 + sunit * 16;
    for (int chunk = 0; chunk < 32; ++chunk) {
      __syncthreads();
#pragma unroll
      for (int i = 0; i < 4; ++i) async16(a0 + i * 32768, ldsA + i * 1024);
#pragma unroll
      for (int i = 0; i < 4; ++i) async16(b0 + i * 32768, ldsB + i * 1024);
      __syncthreads();
#pragma unroll
      for (int ks = 0; ks < 2; ++ks) {
        h8 ah[2], al[2], bh[2], bl[2];
#pragma unroll
        for (int mt = 0; mt < 2; ++mt) {
          ah[mt] = *(const h8*)(lds + rowA0 + mt * 4096 + uoff[ks][0]);
          al[mt] = *(const h8*)(lds + rowA0 + mt * 4096 + uoff[ks][1]);
        }
#pragma unroll
        for (int nt = 0; nt < 2; ++nt) {
          bh[nt] = *(const h8*)(lds + rowB0 + nt * 4096 + uoff[ks][0]);
          bl[nt] = *(const h8*)(lds + rowB0 + nt * 4096 + uoff[ks][1]);
        }
#pragma unroll
        for (int mt = 0; mt < 2; ++mt)
#pragma unroll
          for (int nt = 0; nt < 2; ++nt) {
            acc[mt][nt] = __builtin_amdgcn_mfma_f32_32x32x16_f16(ah[mt], bh[nt], acc[mt][nt], 0, 0, 0);
            acc[mt][nt] = __builtin_amdgcn_mfma_f32_32x32x16_f16(ah[mt], bl[nt], acc[mt][nt], 0, 0, 0);
            acc[mt][nt] = __builtin_amdgcn_mfma_f32_32x32x16_f16(al[mt], bh[nt], acc[mt][nt], 0, 0, 0);
          }
      }
      a0 += 128;
      b0 += 128;
    }
  }

  const int wm0 = (wid >> 1) * 64, wn0 = (wid & 1) * 64;
  if (EPI == 0) {
    float* C = Cf + z * zC;
#pragma unroll
    for (int nt = 0; nt < 2; ++nt) {
      const int col = bn0 + wn0 + nt * 32 + ln31;
      const float bv = bias ? bias[col] : 0.0f;
#pragma unroll
      for (int mt = 0; mt < 2; ++mt) {
#pragma unroll
        for (int q = 0; q < 4; ++q) {
#pragma unroll
          for (int i = 0; i < 4; ++i) {
            const int row = bm0 + wm0 + mt * 32 + q * 8 + half * 4 + i;
            C[(long)row * 1024 + col] = acc[mt][nt][q * 4 + i] * scale + bv;
          }
        }
      }
    }
  } else {
    // transposed split store: rows (b,s) -> Ct[b][col][s]
    const long b = bm0 >> 10;
    char* Tb = Ct + b * (4 * MB);
    const int sbase = bm0 & 1023;
#pragma unroll
    for (int nt = 0; nt < 2; ++nt) {
      const int n = bn0 + wn0 + nt * 32 + ln31;
      const float bv = bias ? bias[n] : 0.0f;
#pragma unroll
      for (int mt = 0; mt < 2; ++mt) {
#pragma unroll
        for (int q = 0; q < 4; ++q) {
          const int sl = sbase + wm0 + mt * 32 + q * 8 + half * 4;
          h4 hv, lv;
#pragma unroll
          for (int i = 0; i < 4; ++i) {
            float y = acc[mt][nt][q * 4 + i] * scale + bv;
            _Float16 h = (_Float16)y;
            hv[i] = h;
            lv[i] = (_Float16)(y - (float)h);
          }
          char* dst = Tb + (long)n * 4096 + (sl >> 3) * 32 + (sl & 7) * 2;
          *(h4*)dst = hv;
          *(h4*)(dst + 16) = lv;
        }
      }
    }
  }
}

// softmax over 1024 per row, writes split-pair fp16 attn. 128 threads/row.
__launch_bounds__(128)
__global__ void softmax_split(const float* __restrict__ S, char* __restrict__ attn) {
  const long row = blockIdx.x;
  const int t = threadIdx.x;
  const float* p = S + row * 1024 + t * 8;
  float4 a = *(const float4*)p, b = *(const float4*)(p + 4);
  float v[8] = {a.x, a.y, a.z, a.w, b.x, b.y, b.z, b.w};
  float m = v[0];
#pragma unroll
  for (int j = 1; j < 8; ++j) m = fmaxf(m, v[j]);
  m = wave_max(m);
  __shared__ float redm[2], reds[2];
  const int wave = t >> 6, lane = t & 63;
  if (lane == 0) redm[wave] = m;
  __syncthreads();
  m = fmaxf(redm[0], redm[1]);
  float s = 0.f;
#pragma unroll
  for (int j = 0; j < 8; ++j) {
    v[j] = __expf(v[j] - m);
    s += v[j];
  }
  s = wave_sum(s);
  if (lane == 0) reds[wave] = s;
  __syncthreads();
  const float inv = 1.0f / (reds[0] + reds[1]);
#pragma unroll
  for (int j = 0; j < 8; ++j) v[j] *= inv;
  h8 hi, lo;
  split8(v, hi, lo);
  char* dst = attn + row * 4096 + t * 32;
  *(h8*)dst = hi;
  *(h8*)(dst + 16) = lo;
}

// complex layernorm rows of 1024: z = inr + i*ini -> d_out (real | imag halves)
__launch_bounds__(256)
__global__ void complex_ln(const float* __restrict__ inr, const float* __restrict__ ini,
                           float* __restrict__ outr, float* __restrict__ outi,
                           const float* __restrict__ a2, const float* __restrict__ b2) {
  const long row = blockIdx.x;
  const int tid = threadIdx.x;
  const float* xr = inr + row * 1024;
  const float* xi = ini + row * 1024;
  float4 r4 = *(const float4*)(xr + tid * 4);
  float4 i4 = *(const float4*)(xi + tid * 4);
  float sx = r4.x + r4.y + r4.z + r4.w;
  float sy = i4.x + i4.y + i4.z + i4.w;
  float sxx = r4.x * r4.x + r4.y * r4.y + r4.z * r4.z + r4.w * r4.w;
  float syy = i4.x * i4.x + i4.y * i4.y + i4.z * i4.z + i4.w * i4.w;
  float sxy = r4.x * i4.x + r4.y * i4.y + r4.z * i4.z + r4.w * i4.w;
  sx = wave_sum(sx); sy = wave_sum(sy);
  sxx = wave_sum(sxx); syy = wave_sum(syy); sxy = wave_sum(sxy);
  __shared__ float red[4][5];
  const int wave = tid >> 6, lane = tid & 63;
  if (lane == 0) {
    red[wave][0] = sx; red[wave][1] = sy; red[wave][2] = sxx;
    red[wave][3] = syy; red[wave][4] = sxy;
  }
  __syncthreads();
  sx = red[0][0] + red[1][0] + red[2][0] + red[3][0];
  sy = red[0][1] + red[1][1] + red[2][1] + red[3][1];
  sxx = red[0][2] + red[1][2] + red[2][2] + red[3][2];
  syy = red[0][3] + red[1][3] + red[2][3] + red[3][3];
  sxy = red[0][4] + red[1][4] + red[2][4] + red[3][4];
  const float invN = 1.0f / 1024.0f;
  const float mx = sx * invN, my = sy * invN;
  const float vx = (sxx * invN - mx * mx) - (syy * invN - my * my);
  const float vy = 2.0f * (sxy * invN - mx * my);
  const float wx = vx + 1e-6f, wy = vy;
  const float rm = sqrtf(wx * wx + wy * wy);
  const float sre = sqrtf(fmaxf(rm + wx, 0.0f) * 0.5f);
  const float sim = copysignf(sqrtf(fmaxf(rm - wx, 0.0f) * 0.5f), wy);
  const float ir = 1.0f / fmaxf(rm, 1e-30f);
  float4 a4 = *(const float4*)(a2 + tid * 4);
  float4 b4 = *(const float4*)(b2 + tid * 4);
  float4 orr, oii;
  {
    float zx = r4.x - mx, zy = i4.x - my;
    orr.x = a4.x * ((zx * sre + zy * sim) * ir) + b4.x;
    oii.x = a4.x * ((zy * sre - zx * sim) * ir);
  }
  {
    float zx = r4.y - mx, zy = i4.y - my;
    orr.y = a4.y * ((zx * sre + zy * sim) * ir) + b4.y;
    oii.y = a4.y * ((zy * sre - zx * sim) * ir);
  }
  {
    float zx = r4.z - mx, zy = i4.z - my;
    orr.z = a4.z * ((zx * sre + zy * sim) * ir) + b4.z;
    oii.z = a4.z * ((zy * sre - zx * sim) * ir);
  }
  {
    float zx = r4.w - mx, zy = i4.w - my;
    orr.w = a4.w * ((zx * sre + zy * sim) * ir) + b4.w;
    oii.w = a4.w * ((zy * sre - zx * sim) * ir);
  }
  *(float4*)(outr + row * 1024 + tid * 4) = orr;
  *(float4*)(outi + row * 1024 + tid * 4) = oii;
}

extern "C" void kernel_launch(void* const* d_in, const int* in_sizes, int n_in,
                              void* d_out, int out_size, void* d_ws, size_t ws_size,
                              hipStream_t stream) {
  const float* X[6];
  for (int i = 0; i < 6; ++i) X[i] = (const float*)d_in[i];
  const float* W[6];
  const float* bia[6];
  for (int i = 0; i < 6; ++i) {
    W[i] = (const float*)d_in[6 + 2 * i];
    bia[i] = (const float*)d_in[7 + 2 * i];
  }
  const float* a2 = (const float*)d_in[18];
  const float* b2 = (const float*)d_in[19];

  char* ws = (char*)d_ws;
  char* qr = ws;
  char* qi = ws + 64 * MB;
  char* ki = ws + 128 * MB;
  char* krT = ws + 192 * MB;
  char* vrT = ws + 256 * MB;
  char* viT = ws + 320 * MB;
  char* Wsp[6];
  for (int i = 0; i < 6; ++i) Wsp[i] = ws + 384 * MB + (long)i * 4 * MB;

  char* dob = (char*)d_out;
  char* Xsp = dob;                       // [0, 64MB)
  float* F0 = (float*)(dob + 64 * MB);   // [64, 128MB)
  float* Sf = (float*)dob;               // scores f32 (after Xsp dead)
  char* attn = dob + 64 * MB;            // attn split (after F0 dead)
  float* outr = (float*)ws;              // over qr_sp
  float* outi = (float*)(ws + 64 * MB);  // over qi_sp

  dim3 blk(256);
  dim3 proj_g(8, 128, 1), bat_g(8, 8, 16);

  // W splits
  for (int i = 0; i < 6; ++i)
    split_pass<<<dim3(512), blk, 0, stream>>>(W[i], Wsp[i], 131072L);

  // qr = q_real @ Wq_r^T + b  (f32 -> F0 -> split)
  split_pass<<<dim3(8192), blk, 0, stream>>>(X[0], Xsp, 2097152L);
  gemm_sp<0><<<proj_g, blk, 0, stream>>>(Xsp, Wsp[0], nullptr, nullptr, 1, bia[0], F0, nullptr, 1.0f, 0, 0, 0);
  split_pass<<<dim3(8192), blk, 0, stream>>>(F0, qr, 2097152L);
  // qi
  split_pass<<<dim3(8192), blk, 0, stream>>>(X[1], Xsp, 2097152L);
  gemm_sp<0><<<proj_g, blk, 0, stream>>>(Xsp, Wsp[1], nullptr, nullptr, 1, bia[1], F0, nullptr, 1.0f, 0, 0, 0);
  split_pass<<<dim3(8192), blk, 0, stream>>>(F0, qi, 2097152L);
  // ki
  split_pass<<<dim3(8192), blk, 0, stream>>>(X[3], Xsp, 2097152L);
  gemm_sp<0><<<proj_g, blk, 0, stream>>>(Xsp, Wsp[3], nullptr, nullptr, 1, bia[3], F0, nullptr, 1.0f, 0, 0, 0);
  split_pass<<<dim3(8192), blk, 0, stream>>>(F0, ki, 2097152L);
  // krT (transposed split epilogue)
  split_pass<<<dim3(8192), blk, 0, stream>>>(X[2], Xsp, 2097152L);
  gemm_sp<1><<<proj_g, blk, 0, stream>>>(Xsp, Wsp[2], nullptr, nullptr, 1, bia[2], nullptr, krT, 1.0f, 0, 0, 0);
  // vrT
  split_pass<<<dim3(8192), blk, 0, stream>>>(X[4], Xsp, 2097152L);
  gemm_sp<1><<<proj_g, blk, 0, stream>>>(Xsp, Wsp[4], nullptr, nullptr, 1, bia[4], nullptr, vrT, 1.0f, 0, 0, 0);
  // viT
  split_pass<<<dim3(8192), blk, 0, stream>>>(X[5], Xsp, 2097152L);
  gemm_sp<1><<<proj_g, blk, 0, stream>>>(Xsp, Wsp[5], nullptr, nullptr, 1, bia[5], nullptr, viT, 1.0f, 0, 0, 0);

  // scores = 0.125*(qr @ krT^T + qi @ ki^T), fused K=2048
  gemm_sp<0><<<bat_g, blk, 0, stream>>>(qr, krT, qi, ki, 2, nullptr, Sf, nullptr, 0.125f,
                                        4 * MB, 4 * MB, 1048576L);
  // softmax + split
  softmax_split<<<dim3(16384), dim3(128), 0, stream>>>(Sf, attn);
  // out = attn @ v
  gemm_sp<0><<<bat_g, blk, 0, stream>>>(attn, vrT, nullptr, nullptr, 1, nullptr, outr, nullptr, 1.0f,
                                        4 * MB, 4 * MB, 1048576L);
  gemm_sp<0><<<bat_g, blk, 0, stream>>>(attn, viT, nullptr, nullptr, 1, nullptr, outi, nullptr, 1.0f,
                                        4 * MB, 4 * MB, 1048576L);
  // complex layernorm ws -> d_out
  complex_ln<<<dim3(16384), blk, 0, stream>>>(outr, outi, (float*)d_out,
                                              (float*)(dob + 64 * MB), a2, b2);
}